// Round 14
// baseline (185.983 us; speedup 1.0000x reference)
//
#include <hip/hip_runtime.h>

// QuantFinanceAttention: B=2, T=2048, C=1024, H=16, dk=64. fp32 I/O, bf16 MFMA internals.
// cvt(x -> A-FRAGMENT-major, weights row-major) | QKV gemm v6b (r13-exact): HYBRID feed,
// A-frags streamed from L2 (named-reg ping-pong), B via 4-buffer LDS counted vmcnt(3) |
// flash v8: 4-WAVE KEY SPLIT (256 thr; wave w owns chunks w, w+4, ... -> longest path
// halves, tail halves) + setprio(1) around MFMA clusters [T5, m191 regime]; 2-round LDS
// combine tree (24KB); no LDS staging, K one-chunk-ahead prefetch, in-register softmax |
// proj v2 (r13-exact). History: no-LDS GEMM regressed (r8); conflict fixes neutral
// (r7/r10); lambda-pointer pipeline alloca'd -> vmcnt pollution NaN (r12, rule #20).

typedef __bf16 bf16x8 __attribute__((ext_vector_type(8)));
typedef float f32x4 __attribute__((ext_vector_type(4)));
typedef float f32x16 __attribute__((ext_vector_type(16)));
typedef unsigned short u16x8 __attribute__((ext_vector_type(8)));

__device__ __forceinline__ unsigned short f2bf(float f) {
    union { float f; unsigned int u; } c; c.f = f;
    unsigned int u = c.u;
    unsigned int r = u + 0x7fffu + ((u >> 16) & 1u);  // RNE
    return (unsigned short)(r >> 16);
}
__device__ __forceinline__ unsigned cvtpk(float lo, float hi) {
    unsigned r;
    asm("v_cvt_pk_bf16_f32 %0, %1, %2" : "=v"(r) : "v"(lo), "v"(hi));
    return r;
}
// Exchange across the lane<32 / lane>=32 halves:
//   ret0[l<32]=a[l], ret0[l>=32]=b[l-32];  ret1[l<32]=a[l+32], ret1[l>=32]=b[l]
__device__ __forceinline__ void plswap(unsigned a, unsigned b, unsigned& r0, unsigned& r1) {
#if __has_builtin(__builtin_amdgcn_permlane32_swap)
    auto s = __builtin_amdgcn_permlane32_swap(a, b, false, false);
    r0 = (unsigned)s[0]; r1 = (unsigned)s[1];
#else
    const int hh = (int)(threadIdx.x & 63) >> 5;
    const unsigned oa = (unsigned)__shfl_xor((int)a, 32);
    const unsigned ob = (unsigned)__shfl_xor((int)b, 32);
    r0 = hh ? ob : a;
    r1 = hh ? b : oa;
#endif
}
__device__ __forceinline__ void stage8_f32(unsigned short* dst, const float* src) {
    const float4 a = *(const float4*)src;
    const float4 b = *(const float4*)(src + 4);
    u16x8 v;
    v[0] = f2bf(a.x); v[1] = f2bf(a.y); v[2] = f2bf(a.z); v[3] = f2bf(a.w);
    v[4] = f2bf(b.x); v[5] = f2bf(b.y); v[6] = f2bf(b.z); v[7] = f2bf(b.w);
    *(u16x8*)dst = v;
}
__device__ __forceinline__ void async16(const unsigned short* g, unsigned short* l) {
    __builtin_amdgcn_global_load_lds(
        (const __attribute__((address_space(1))) void*)g,
        (__attribute__((address_space(3))) void*)l, 16, 0, 0);
}

// A-fragment-major layout (shorts) for a [R][1024] bf16 matrix:
//   addr(row, k) = (row>>4)*16384 + (k>>5)*512 + ((k>>3)&3)*128 + (row&15)*8 + (k&7)
__global__ __launch_bounds__(256) void cvt_all(
    const float* __restrict__ x, const float* __restrict__ Wq, const float* __restrict__ Wk,
    const float* __restrict__ Wv, const float* __restrict__ Wo,
    unsigned short* __restrict__ dst, int hasX, int n8)
{
    const int i = blockIdx.x * 256 + threadIdx.x;
    if (i >= n8) return;
    int r = i;
    const float* src; size_t soff;
    const int xg = hasX ? 524288 : 0;
    if (r < xg) {                            // x -> A-fragment-major (big path only)
        const int lane16 = r & 15, sub = (r >> 4) & 3, kb = (r >> 6) & 31, rb = r >> 11;
        src = x; soff = (size_t)(rb * 16 + lane16) * 128 + kb * 4 + sub;
    } else {
        r -= xg;
        const int w = r >> 17, o = r & 131071;
        src = (w == 0) ? Wq : (w == 1) ? Wk : (w == 2) ? Wv : Wo;
        soff = o;                            // weights: row-major
    }
    stage8_f32(&dst[(size_t)i * 8], &src[soff * 8]);
}

// Flash fragment layouts (per bh = 131072 shorts), written by the qkv epilogue:
//  Q/K: addr = bh*131072 + ((t>>5)*4 + (d>>4))*512 + (((d>>3)&1)*32 + (t&31))*8 + (d&7)
//  V:   addr = bh*131072 + ((t>>5)*4 + (d>>5)*2 + ((t>>4)&1))*512 + (((t>>3)&1)*32 + (d&31))*8 + (t&7)
template<int A_BF16>
__global__ __launch_bounds__(512) void gemm_qkv(
    const void* __restrict__ Av, const unsigned short* __restrict__ Wb,
    unsigned short* __restrict__ outv, const float* __restrict__ swg)
{
    constexpr int K = 1024, BK = 32;
    __shared__ __align__(16) unsigned short Bs[4][128 * BK];   // 32KB (fallback: 2,3 = As)
    const int tid = threadIdx.x;
    const int wid = tid >> 6, lane = tid & 63, g = lane >> 4, l = lane & 15;
    const int wm = (wid & 3) * 32, wn = (wid >> 2) * 64;

    // XCD-chunked bijective swizzle (768 blocks, 768%8==0)
    const int lin = blockIdx.x + (blockIdx.y << 3) + (blockIdx.z << 8);
    const int wg  = (lin & 7) * 96 + (lin >> 3);
    const int bx = wg & 7, by = (wg >> 3) & 31, bz = wg >> 8;
    const int m0 = by * 128, n0 = bx * 128;
    const int z = bz;
    const unsigned short* W = Wb + (size_t)z * 1048576;

    f32x4 acc[2][4];
#pragma unroll
    for (int i = 0; i < 2; ++i)
#pragma unroll
        for (int j = 0; j < 4; ++j) acc[i][j] = f32x4{0.f, 0.f, 0.f, 0.f};

    const int r  = tid >> 2;                              // staged row 0..127
    const int cs = (((tid & 3) ^ ((tid >> 3) & 3)) * 8);  // pre-swizzled source chunk
    const int xg = (g ^ ((l >> 1) & 3)) * 8;              // read-side chunk

    if (A_BF16) {
        const unsigned short* Ab = (const unsigned short*)Av;
        Ab += (size_t)((m0 + wm) >> 4) * 16384 + g * 128 + l * 8;
        const unsigned short* Ab1 = Ab + 16384;
#define QSTAGE(buf, k0) async16(&W[(size_t)(n0 + r) * K + (k0) + cs], &Bs[buf][wid * 512])
        QSTAGE(0, 0);
        QSTAGE(1, BK);
        bf16x8 afX0 = *(const bf16x8*)(Ab);
        bf16x8 afX1 = *(const bf16x8*)(Ab1);
        bf16x8 afY0, afY1;
#define QSTEP(ks, buf, C0, C1, N0, N1, PRE, STG, WAITN)                                      \
    {                                                                                        \
        asm volatile("s_waitcnt vmcnt(" #WAITN ")" ::: "memory");                            \
        __builtin_amdgcn_s_barrier();                                                        \
        const unsigned short* Bsr = Bs[buf];                                                 \
        bf16x8 b0 = *(const bf16x8*)&Bsr[(wn +  0 + l) * BK + xg];                           \
        bf16x8 b1 = *(const bf16x8*)&Bsr[(wn + 16 + l) * BK + xg];                           \
        bf16x8 b2 = *(const bf16x8*)&Bsr[(wn + 32 + l) * BK + xg];                           \
        bf16x8 b3 = *(const bf16x8*)&Bsr[(wn + 48 + l) * BK + xg];                           \
        if (PRE) { N0 = *(const bf16x8*)(Ab  + (size_t)((ks) + 1) * 512);                    \
                   N1 = *(const bf16x8*)(Ab1 + (size_t)((ks) + 1) * 512); }                  \
        acc[0][0] = __builtin_amdgcn_mfma_f32_16x16x32_bf16(C0, b0, acc[0][0], 0, 0, 0);     \
        acc[0][1] = __builtin_amdgcn_mfma_f32_16x16x32_bf16(C0, b1, acc[0][1], 0, 0, 0);     \
        acc[0][2] = __builtin_amdgcn_mfma_f32_16x16x32_bf16(C0, b2, acc[0][2], 0, 0, 0);     \
        acc[0][3] = __builtin_amdgcn_mfma_f32_16x16x32_bf16(C0, b3, acc[0][3], 0, 0, 0);     \
        acc[1][0] = __builtin_amdgcn_mfma_f32_16x16x32_bf16(C1, b0, acc[1][0], 0, 0, 0);     \
        acc[1][1] = __builtin_amdgcn_mfma_f32_16x16x32_bf16(C1, b1, acc[1][1], 0, 0, 0);     \
        acc[1][2] = __builtin_amdgcn_mfma_f32_16x16x32_bf16(C1, b2, acc[1][2], 0, 0, 0);     \
        acc[1][3] = __builtin_amdgcn_mfma_f32_16x16x32_bf16(C1, b3, acc[1][3], 0, 0, 0);     \
        if (STG) QSTAGE(((buf) + 2) & 3, ((ks) + 2) * BK);                                   \
    }
        for (int t = 0; t < 7; ++t) {          // ks = 0..27
            const int k4 = t * 4;
            QSTEP(k4 + 0, 0, afX0, afX1, afY0, afY1, 1, 1, 3)
            QSTEP(k4 + 1, 1, afY0, afY1, afX0, afX1, 1, 1, 3)
            QSTEP(k4 + 2, 2, afX0, afX1, afY0, afY1, 1, 1, 3)
            QSTEP(k4 + 3, 3, afY0, afY1, afX0, afX1, 1, 1, 3)
        }
        QSTEP(28, 0, afX0, afX1, afY0, afY1, 1, 1, 3)      // stages Bs[2] <- ks 30
        QSTEP(29, 1, afY0, afY1, afX0, afX1, 1, 1, 3)      // stages Bs[3] <- ks 31
        QSTEP(30, 2, afX0, afX1, afY0, afY1, 1, 0, 3)      // prefetch A for ks 31
        QSTEP(31, 3, afY0, afY1, afX0, afX1, 0, 0, 0)
#undef QSTEP
#undef QSTAGE
    } else {
        // fallback: fp32 A reg-staged into Bs[2..3] with matching write-side swizzle
        const int cc = (tid & 3);                  // source chunk (A reg-staged path)
        const int sl = (cc ^ ((r >> 1) & 3)) * 8;  // swizzled slot for row r
        auto stageF = [&](int buf, int k0) {
            const float* A = (const float*)Av;
            stage8_f32(&Bs[2 + buf][r * BK + sl], &A[(size_t)(m0 + r) * K + k0 + cc * 8]);
            async16(&W[(size_t)(n0 + r) * K + k0 + cs], &Bs[buf][wid * 512]);
        };
        stageF(0, 0);
        __syncthreads();
        for (int k0 = 0; k0 < K; k0 += BK) {
            const int cur = (k0 >> 5) & 1;
            if (k0 + BK < K) stageF(cur ^ 1, k0 + BK);
            bf16x8 af[2], bfr[4];
#pragma unroll
            for (int im = 0; im < 2; ++im) af[im]  = *(const bf16x8*)&Bs[2 + cur][(wm + im * 16 + l) * BK + xg];
#pragma unroll
            for (int in = 0; in < 4; ++in) bfr[in] = *(const bf16x8*)&Bs[cur][(wn + in * 16 + l) * BK + xg];
#pragma unroll
            for (int im = 0; im < 2; ++im)
#pragma unroll
                for (int in = 0; in < 4; ++in)
                    acc[im][in] = __builtin_amdgcn_mfma_f32_16x16x32_bf16(af[im], bfr[in], acc[im][in], 0, 0, 0);
            __syncthreads();
        }
    }

    unsigned short* outq = outv + (size_t)z * 4194304;
    if (z < 2) {
        const int hq = (n0 + wn) >> 6;               // head (constant per thread)
        float freq[2];
#pragma unroll
        for (int in = 0; in < 2; ++in)
            freq[in] = exp2f(-(float)(in * 16 + l) * 0.41524101186f);  // log2(10000)/32
#pragma unroll
        for (int im = 0; im < 2; ++im)
#pragma unroll
            for (int i = 0; i < 4; ++i) {
                const int m = m0 + wm + im * 16 + g * 4 + i;
                const int b = m >> 11, t = m & 2047;
                float fw = 1.0f;
                if (z == 1) fw = 0.18033688011f * swg[(b << 11) + t];  // SCALE*log2(e)*w
                const size_t fq = (size_t)((b << 4) + hq) * 131072
                                + (size_t)((t >> 5) << 2) * 512
                                + (size_t)((((l >> 3) & 1) << 5) + (t & 31)) * 8 + (l & 7);
#pragma unroll
                for (int in = 0; in < 2; ++in) {
                    const float ang = (float)t * freq[in];
                    const float cs2 = __cosf(ang), sn = __sinf(ang);
                    const float x1 = acc[im][in][i], x2 = acc[im][in + 2][i];
                    outq[fq + (size_t)in * 512]       = f2bf((x1 * cs2 - x2 * sn) * fw);
                    outq[fq + (size_t)(in + 2) * 512] = f2bf((x2 * cs2 + x1 * sn) * fw);
                }
            }
    } else {
        // V fragments: 4 consecutive t -> 4 consecutive slots within one lane group -> ushort4
#pragma unroll
        for (int im = 0; im < 2; ++im)
#pragma unroll
            for (int in = 0; in < 4; ++in) {
                const int n = n0 + wn + in * 16 + l;
                const int h = n >> 6, d = n & 63;
                const int mb = m0 + wm + im * 16 + g * 4;
                const int bq = mb >> 11, t0 = mb & 2047;
                ushort4 pk;
                pk.x = f2bf(acc[im][in][0]); pk.y = f2bf(acc[im][in][1]);
                pk.z = f2bf(acc[im][in][2]); pk.w = f2bf(acc[im][in][3]);
                const size_t fv = (size_t)((bq << 4) + h) * 131072
                                + (size_t)(((t0 >> 5) << 2) + ((d >> 5) << 1) + ((t0 >> 4) & 1)) * 512
                                + (size_t)((((t0 >> 3) & 1) << 5) + (d & 31)) * 8 + (t0 & 7);
                *(ushort4*)&outq[fv] = pk;
            }
    }
}

// Projection v2 (r13-exact): C = A(bf16 row-major)[4096,1024] x Wo^T + bias, 64x128
// tile -> 512 blocks of 512 threads / 8 waves. Wave tile 32x32. Asymmetric staging:
// waves 0-3 load A+B, waves 4-7 B only -> per-wave counted vmcnt(2)/vmcnt(1).
__global__ __launch_bounds__(512) void gemm_proj(
    const unsigned short* __restrict__ A, const unsigned short* __restrict__ W,
    float* __restrict__ out, const float* __restrict__ bias)
{
    constexpr int K = 1024, BK = 32, NS = K / BK;
    __shared__ __align__(16) unsigned short As[3][64 * BK];
    __shared__ __align__(16) unsigned short Bs[3][128 * BK];
    const int tid = threadIdx.x;
    const int wid = tid >> 6, lane = tid & 63, g = lane >> 4, l = lane & 15;
    const int wm = (wid & 1) * 32, wn = (wid >> 1) * 32;

    const int lin = blockIdx.x + (blockIdx.y << 3);     // 512 blocks, 512%8==0
    const int wg  = (lin & 7) * 64 + (lin >> 3);
    const int m0 = (wg >> 3) * 64, n0 = (wg & 7) * 128;

    f32x4 acc[2][2];
#pragma unroll
    for (int i = 0; i < 2; ++i)
#pragma unroll
        for (int j = 0; j < 2; ++j) acc[i][j] = f32x4{0.f, 0.f, 0.f, 0.f};

    const int r  = tid >> 2;                              // B row 0..127; A row 0..63 (tid<256)
    const int cs = (((tid & 3) ^ ((tid >> 3) & 3)) * 8);
    const int xg = (g ^ ((l >> 1) & 3)) * 8;

    auto stage = [&](int buf, int k0) {
        if (tid < 256) async16(&A[(size_t)(m0 + r) * K + k0 + cs], &As[buf][wid * 512]);
        async16(&W[(size_t)(n0 + r) * K + k0 + cs], &Bs[buf][wid * 512]);
    };
    auto compute = [&](int buf) {
        const unsigned short* Asr = As[buf];
        const unsigned short* Bsr = Bs[buf];
        bf16x8 af[2], bfr[2];
#pragma unroll
        for (int im = 0; im < 2; ++im) af[im]  = *(const bf16x8*)&Asr[(wm + im * 16 + l) * BK + xg];
#pragma unroll
        for (int in = 0; in < 2; ++in) bfr[in] = *(const bf16x8*)&Bsr[(wn + in * 16 + l) * BK + xg];
#pragma unroll
        for (int im = 0; im < 2; ++im)
#pragma unroll
            for (int in = 0; in < 2; ++in)
                acc[im][in] = __builtin_amdgcn_mfma_f32_16x16x32_bf16(af[im], bfr[in], acc[im][in], 0, 0, 0);
    };

    stage(0, 0);
    stage(1, BK);
    for (int ks = 0; ks < NS; ++ks) {
        if (ks + 1 < NS) {
            if (wid < 4) asm volatile("s_waitcnt vmcnt(2)" ::: "memory");
            else         asm volatile("s_waitcnt vmcnt(1)" ::: "memory");
        } else {
            asm volatile("s_waitcnt vmcnt(0)" ::: "memory");
        }
        __builtin_amdgcn_s_barrier();
        compute(ks % 3);
        if (ks + 2 < NS) stage((ks + 2) % 3, (ks + 2) * BK);
    }

#pragma unroll
    for (int im = 0; im < 2; ++im)
#pragma unroll
        for (int in = 0; in < 2; ++in) {
            const int n = n0 + wn + in * 16 + l;
#pragma unroll
            for (int i = 0; i < 4; ++i) {
                const int m = m0 + wm + im * 16 + g * 4 + i;
                out[(size_t)m * 1024 + n] = acc[im][in][i] + bias[n];
            }
        }
}

// Flash v8: 2048 blocks x 256 threads (4 waves), block = (bh, 32q strip p),
// longest-first. Wave wid owns key chunks c = wid, wid+4, ... <= p -> longest wave
// path is 16 iters (was 32), halving the drain tail. No LDS staging, barrier-free
// loop, K one-chunk-ahead register prefetch, setprio(1) around MFMA clusters [T5].
// Swapped QK^T -> in-register softmax (16 exp2 + 8 cvt_pk + 4 permlane32_swap).
// K pre-scaled by SCALE*log2e*w[key]. Constant-max softmax -> partials additive:
// 2-round LDS combine tree (w1,w3 write | w0,w2 add | w2 writes | w0 finalizes).
__global__ __launch_bounds__(256, 2) void flash_attn(
    const unsigned short* __restrict__ Qf, const unsigned short* __restrict__ Kf,
    const unsigned short* __restrict__ Vf, const float* __restrict__ sbias,
    const float* __restrict__ sw, unsigned short* __restrict__ attn)
{
    constexpr int T = 2048;
    __shared__ float Cmb[6144];             // 2 regions x (2x16x64 oacc + 16x64 lrow) = 24 KB

    const int tid = threadIdx.x, wid = tid >> 6, lane = tid & 63;
    const int hl = lane & 31, hh = lane >> 5;
    const int id = blockIdx.x;
    const int p  = 63 - (id >> 5);          // globally longest-first
    const int bh = id & 31, b = bh >> 4, h = bh & 15;
    const size_t fb = (size_t)bh * 131072;  // fragment base (Q/K/V identical shape)
    const float bias = sbias[h];
    const float* swb = sw + b * T;

    bf16x8 onef;
#pragma unroll
    for (int j = 0; j < 8; ++j) onef[j] = (__bf16)1.0f;

    const int q0 = p * 32;
    bf16x8 qf[4];
#pragma unroll
    for (int ks = 0; ks < 4; ++ks)
        qf[ks] = *(const bf16x8*)&Qf[fb + (size_t)(p * 4 + ks) * 512 + lane * 8];

    f32x16 oacc[2], lrow;
#pragma unroll
    for (int r = 0; r < 16; ++r) { oacc[0][r] = 0.f; oacc[1][r] = 0.f; lrow[r] = 0.f; }

    // prologue: load K for this wave's first chunk
    bf16x8 kcur[4];
    if (wid <= p) {
        const unsigned short* kb = &Kf[fb + (size_t)wid * 2048 + lane * 8];
#pragma unroll
        for (int ks = 0; ks < 4; ++ks) kcur[ks] = *(const bf16x8*)&kb[ks * 512];
    }

    for (int c = wid; c <= p; c += 4) {
        // S^T = K' Q^T (32k x 32q): lane holds q = q0+hl, rows r -> keys
        f32x16 sx;
#pragma unroll
        for (int r = 0; r < 16; ++r) sx[r] = 0.f;
        __builtin_amdgcn_s_setprio(1);
        sx = __builtin_amdgcn_mfma_f32_32x32x16_bf16(kcur[0], qf[0], sx, 0, 0, 0);
        sx = __builtin_amdgcn_mfma_f32_32x32x16_bf16(kcur[1], qf[1], sx, 0, 0, 0);
        sx = __builtin_amdgcn_mfma_f32_32x32x16_bf16(kcur[2], qf[2], sx, 0, 0, 0);
        sx = __builtin_amdgcn_mfma_f32_32x32x16_bf16(kcur[3], qf[3], sx, 0, 0, 0);
        __builtin_amdgcn_s_setprio(0);

        // prefetch next chunk's K (kcur regs dead after the MFMAs above)
        if (c + 4 <= p) {
            const unsigned short* kb = &Kf[fb + (size_t)(c + 4) * 2048 + lane * 8];
#pragma unroll
            for (int ks = 0; ks < 4; ++ks) kcur[ks] = *(const bf16x8*)&kb[ks * 512];
        }

        // issue V loads now; softmax below covers their L2 latency
        const unsigned short* vb = &Vf[fb + (size_t)c * 2048 + lane * 8];
        const bf16x8 vf00 = *(const bf16x8*)&vb[0];      // (dt0,ks0)
        const bf16x8 vf01 = *(const bf16x8*)&vb[512];    // (dt0,ks1)
        const bf16x8 vf10 = *(const bf16x8*)&vb[1024];   // (dt1,ks0)
        const bf16x8 vf11 = *(const bf16x8*)&vb[1536];   // (dt1,ks1)

        if (bias != 0.0f) {                  // benchmark has sector_bias == 0
            const float bn = bias * 1.44269504f;
#pragma unroll
            for (int r = 0; r < 16; ++r) {
                const int kl = (r & 3) + 8 * (r >> 2) + 4 * hh;
                sx[r] += bn * swb[c * 32 + kl];
            }
        }
        if (c == p) {                        // diagonal chunk: causal mask (key kl <= q hl)
#pragma unroll
            for (int r = 0; r < 16; ++r) {
                const int kl = (r & 3) + 8 * (r >> 2) + 4 * hh;
                sx[r] = (kl <= hl) ? sx[r] : -1e30f;
            }
        }
#pragma unroll
        for (int r = 0; r < 16; ++r) sx[r] = exp2f(sx[r]);

        // pack P -> bf16 A-fragment: 8 cvt_pk + 4 permlane32_swap
        unsigned wds[8];
#pragma unroll
        for (int g2 = 0; g2 < 4; ++g2) {
            wds[g2 * 2]     = cvtpk(sx[g2 * 4],     sx[g2 * 4 + 1]);
            wds[g2 * 2 + 1] = cvtpk(sx[g2 * 4 + 2], sx[g2 * 4 + 3]);
        }
        bf16x8 pf[2];
#pragma unroll
        for (int ks = 0; ks < 2; ++ks) {
            unsigned a0, a1, b0, b1;
            plswap(wds[4 * ks],     wds[4 * ks + 2], a0, a1);
            plswap(wds[4 * ks + 1], wds[4 * ks + 3], b0, b1);
            union { unsigned u[4]; bf16x8 v; } pk_;
            pk_.u[0] = a0; pk_.u[1] = b0;
            pk_.u[2] = a1; pk_.u[3] = b1;
            pf[ks] = pk_.v;
        }

        // rowsum via ones-MFMA + O += P V
        __builtin_amdgcn_s_setprio(1);
        lrow = __builtin_amdgcn_mfma_f32_32x32x16_bf16(pf[0], onef, lrow, 0, 0, 0);
        lrow = __builtin_amdgcn_mfma_f32_32x32x16_bf16(pf[1], onef, lrow, 0, 0, 0);
        oacc[0] = __builtin_amdgcn_mfma_f32_32x32x16_bf16(pf[0], vf00, oacc[0], 0, 0, 0);
        oacc[0] = __builtin_amdgcn_mfma_f32_32x32x16_bf16(pf[1], vf01, oacc[0], 0, 0, 0);
        oacc[1] = __builtin_amdgcn_mfma_f32_32x32x16_bf16(pf[0], vf10, oacc[1], 0, 0, 0);
        oacc[1] = __builtin_amdgcn_mfma_f32_32x32x16_bf16(pf[1], vf11, oacc[1], 0, 0, 0);
        __builtin_amdgcn_s_setprio(0);
    }

    // 2-round combine tree (partials additive under constant-max softmax)
    __syncthreads();
    if (wid & 1) {                           // waves 1,3 -> regions 0,1
        float* C = Cmb + (wid >> 1) * 3072;
#pragma unroll
        for (int dt = 0; dt < 2; ++dt)
#pragma unroll
            for (int r = 0; r < 16; ++r) C[(dt * 16 + r) * 64 + lane] = oacc[dt][r];
#pragma unroll
        for (int r = 0; r < 16; ++r) C[2048 + r * 64 + lane] = lrow[r];
    }
    __syncthreads();
    if (!(wid & 1)) {                        // waves 0,2 add their partner's region
        const float* C = Cmb + (wid >> 1) * 3072;
#pragma unroll
        for (int dt = 0; dt < 2; ++dt)
#pragma unroll
            for (int r = 0; r < 16; ++r) oacc[dt][r] += C[(dt * 16 + r) * 64 + lane];
#pragma unroll
        for (int r = 0; r < 16; ++r) lrow[r] += C[2048 + r * 64 + lane];
    }
    __syncthreads();
    if (wid == 2) {                          // wave 2 publishes its (w2+w3) sum
#pragma unroll
        for (int dt = 0; dt < 2; ++dt)
#pragma unroll
            for (int r = 0; r < 16; ++r) Cmb[(dt * 16 + r) * 64 + lane] = oacc[dt][r];
#pragma unroll
        for (int r = 0; r < 16; ++r) Cmb[2048 + r * 64 + lane] = lrow[r];
    }
    __syncthreads();
    if (wid == 0) {                          // wave 0 finalizes (w0+w1) + (w2+w3)
#pragma unroll
        for (int r = 0; r < 16; ++r) {
            const float li = 1.0f / (lrow[r] + Cmb[2048 + r * 64 + lane]);
            const int row = (r & 3) + 8 * (r >> 2) + 4 * hh;
            const int qr = q0 + row;
#pragma unroll
            for (int dt = 0; dt < 2; ++dt) {
                const float ov = oacc[dt][r] + Cmb[(dt * 16 + r) * 64 + lane];
                attn[(size_t)(b * T + qr) * 1024 + h * 64 + dt * 32 + hl] = f2bf(ov * li);
            }
        }
    }
}

extern "C" void kernel_launch(void* const* d_in, const int* in_sizes, int n_in,
                              void* d_out, int out_size, void* d_ws, size_t ws_size,
                              hipStream_t stream) {
    const float* x  = (const float*)d_in[0];
    const float* Wq = (const float*)d_in[1];
    const float* Wk = (const float*)d_in[2];
    const float* Wv = (const float*)d_in[3];
    const float* Wo = (const float*)d_in[4];
    const float* bo = (const float*)d_in[5];
    const float* sb = (const float*)d_in[6];
    const float* sw = (const float*)d_in[7];

    const size_t QKV_SZ = 4194304;   // shorts per q/k/v tensor
    const size_t W_SZ   = 1048576;   // shorts per weight matrix
    unsigned short* ws16 = (unsigned short*)d_ws;
    const bool big = ws_size >= 2 * (4 * QKV_SZ + 4 * W_SZ);  // 41.9 MB

    if (big) {
        unsigned short* xb    = ws16;            // x (A-fragment-major)
        unsigned short* Wb3   = xb + QKV_SZ;     // Wq,Wk,Wv (row-major)
        unsigned short* Wob   = Wb3 + 3 * W_SZ;  // Wo (row-major)
        unsigned short* qkv   = Wob + W_SZ;      // q,k,v (flash-fragment-major)
        unsigned short* attnb = xb;              // overlay x (dead after QKV gemm)

        cvt_all<<<4096, 256, 0, stream>>>(x, Wq, Wk, Wv, Wo, xb, 1, 1048576);
        gemm_qkv<1><<<dim3(8, 32, 3), 512, 0, stream>>>(xb, Wb3, qkv, sw);
        flash_attn<<<2048, 256, 0, stream>>>(qkv, qkv + QKV_SZ, qkv + 2 * QKV_SZ,
                                             sb, sw, attnb);
        gemm_proj<<<dim3(8, 64), 512, 0, stream>>>(attnb, Wob, (float*)d_out, bo);
    } else {                                     // 33.6 MB fallback
        unsigned short* qkv   = ws16;
        unsigned short* attnb = qkv + 3 * QKV_SZ;
        unsigned short* Wb3   = attnb;           // overlay attn (dead until flash)
        unsigned short* Wob   = qkv;             // overlay q (dead after flash)

        cvt_all<<<1536, 256, 0, stream>>>(x, Wq, Wk, Wv, Wo, Wb3, 0, 393216);
        gemm_qkv<0><<<dim3(8, 32, 3), 512, 0, stream>>>(x, Wb3, qkv, sw);
        flash_attn<<<2048, 256, 0, stream>>>(qkv, qkv + QKV_SZ, qkv + 2 * QKV_SZ,
                                             sb, sw, attnb);
        cvt_all<<<512, 256, 0, stream>>>(x, Wo, Wo, Wo, Wo, Wob, 0, 131072);
        gemm_proj<<<dim3(8, 64), 512, 0, stream>>>(attnb, Wob, (float*)d_out, bo);
    }
}

// Round 15
// 181.510 us; speedup vs baseline: 1.0246x; 1.0246x over previous
//
#include <hip/hip_runtime.h>

// QuantFinanceAttention: B=2, T=2048, C=1024, H=16, dk=64. fp32 I/O, bf16 MFMA internals.
// cvt(x -> A-FRAGMENT-major, weights row-major) | QKV gemm v6b (r13-exact): HYBRID feed,
// A-frags streamed from L2 (named-reg ping-pong), B via 4-buffer LDS counted vmcnt(3) |
// flash v7s: r13's v7 (2-wave, no LDS staging, K one-chunk-ahead prefetch, in-register
// softmax) + ONLY setprio(1) around MFMA clusters [T5, m191: +4-7% attn in exactly this
// independent-block regime] | proj v2 (r13-exact).
// History: 4-wave key split + combine tree REGRESSED (r14: 186 vs 180.5 -- extra
// barriers/LDS, tail not dominant); no-LDS GEMM regressed (r8); conflict fixes neutral
// (r7/r10); lambda-pointer pipeline alloca'd -> vmcnt pollution NaN (r12, rule #20).

typedef __bf16 bf16x8 __attribute__((ext_vector_type(8)));
typedef float f32x4 __attribute__((ext_vector_type(4)));
typedef float f32x16 __attribute__((ext_vector_type(16)));
typedef unsigned short u16x8 __attribute__((ext_vector_type(8)));

__device__ __forceinline__ unsigned short f2bf(float f) {
    union { float f; unsigned int u; } c; c.f = f;
    unsigned int u = c.u;
    unsigned int r = u + 0x7fffu + ((u >> 16) & 1u);  // RNE
    return (unsigned short)(r >> 16);
}
__device__ __forceinline__ unsigned cvtpk(float lo, float hi) {
    unsigned r;
    asm("v_cvt_pk_bf16_f32 %0, %1, %2" : "=v"(r) : "v"(lo), "v"(hi));
    return r;
}
// Exchange across the lane<32 / lane>=32 halves:
//   ret0[l<32]=a[l], ret0[l>=32]=b[l-32];  ret1[l<32]=a[l+32], ret1[l>=32]=b[l]
__device__ __forceinline__ void plswap(unsigned a, unsigned b, unsigned& r0, unsigned& r1) {
#if __has_builtin(__builtin_amdgcn_permlane32_swap)
    auto s = __builtin_amdgcn_permlane32_swap(a, b, false, false);
    r0 = (unsigned)s[0]; r1 = (unsigned)s[1];
#else
    const int hh = (int)(threadIdx.x & 63) >> 5;
    const unsigned oa = (unsigned)__shfl_xor((int)a, 32);
    const unsigned ob = (unsigned)__shfl_xor((int)b, 32);
    r0 = hh ? ob : a;
    r1 = hh ? b : oa;
#endif
}
__device__ __forceinline__ void stage8_f32(unsigned short* dst, const float* src) {
    const float4 a = *(const float4*)src;
    const float4 b = *(const float4*)(src + 4);
    u16x8 v;
    v[0] = f2bf(a.x); v[1] = f2bf(a.y); v[2] = f2bf(a.z); v[3] = f2bf(a.w);
    v[4] = f2bf(b.x); v[5] = f2bf(b.y); v[6] = f2bf(b.z); v[7] = f2bf(b.w);
    *(u16x8*)dst = v;
}
__device__ __forceinline__ void async16(const unsigned short* g, unsigned short* l) {
    __builtin_amdgcn_global_load_lds(
        (const __attribute__((address_space(1))) void*)g,
        (__attribute__((address_space(3))) void*)l, 16, 0, 0);
}

// A-fragment-major layout (shorts) for a [R][1024] bf16 matrix:
//   addr(row, k) = (row>>4)*16384 + (k>>5)*512 + ((k>>3)&3)*128 + (row&15)*8 + (k&7)
__global__ __launch_bounds__(256) void cvt_all(
    const float* __restrict__ x, const float* __restrict__ Wq, const float* __restrict__ Wk,
    const float* __restrict__ Wv, const float* __restrict__ Wo,
    unsigned short* __restrict__ dst, int hasX, int n8)
{
    const int i = blockIdx.x * 256 + threadIdx.x;
    if (i >= n8) return;
    int r = i;
    const float* src; size_t soff;
    const int xg = hasX ? 524288 : 0;
    if (r < xg) {                            // x -> A-fragment-major (big path only)
        const int lane16 = r & 15, sub = (r >> 4) & 3, kb = (r >> 6) & 31, rb = r >> 11;
        src = x; soff = (size_t)(rb * 16 + lane16) * 128 + kb * 4 + sub;
    } else {
        r -= xg;
        const int w = r >> 17, o = r & 131071;
        src = (w == 0) ? Wq : (w == 1) ? Wk : (w == 2) ? Wv : Wo;
        soff = o;                            // weights: row-major
    }
    stage8_f32(&dst[(size_t)i * 8], &src[soff * 8]);
}

// Flash fragment layouts (per bh = 131072 shorts), written by the qkv epilogue:
//  Q/K: addr = bh*131072 + ((t>>5)*4 + (d>>4))*512 + (((d>>3)&1)*32 + (t&31))*8 + (d&7)
//  V:   addr = bh*131072 + ((t>>5)*4 + (d>>5)*2 + ((t>>4)&1))*512 + (((t>>3)&1)*32 + (d&31))*8 + (t&7)
template<int A_BF16>
__global__ __launch_bounds__(512) void gemm_qkv(
    const void* __restrict__ Av, const unsigned short* __restrict__ Wb,
    unsigned short* __restrict__ outv, const float* __restrict__ swg)
{
    constexpr int K = 1024, BK = 32;
    __shared__ __align__(16) unsigned short Bs[4][128 * BK];   // 32KB (fallback: 2,3 = As)
    const int tid = threadIdx.x;
    const int wid = tid >> 6, lane = tid & 63, g = lane >> 4, l = lane & 15;
    const int wm = (wid & 3) * 32, wn = (wid >> 2) * 64;

    // XCD-chunked bijective swizzle (768 blocks, 768%8==0)
    const int lin = blockIdx.x + (blockIdx.y << 3) + (blockIdx.z << 8);
    const int wg  = (lin & 7) * 96 + (lin >> 3);
    const int bx = wg & 7, by = (wg >> 3) & 31, bz = wg >> 8;
    const int m0 = by * 128, n0 = bx * 128;
    const int z = bz;
    const unsigned short* W = Wb + (size_t)z * 1048576;

    f32x4 acc[2][4];
#pragma unroll
    for (int i = 0; i < 2; ++i)
#pragma unroll
        for (int j = 0; j < 4; ++j) acc[i][j] = f32x4{0.f, 0.f, 0.f, 0.f};

    const int r  = tid >> 2;                              // staged row 0..127
    const int cs = (((tid & 3) ^ ((tid >> 3) & 3)) * 8);  // pre-swizzled source chunk
    const int xg = (g ^ ((l >> 1) & 3)) * 8;              // read-side chunk

    if (A_BF16) {
        const unsigned short* Ab = (const unsigned short*)Av;
        Ab += (size_t)((m0 + wm) >> 4) * 16384 + g * 128 + l * 8;
        const unsigned short* Ab1 = Ab + 16384;
#define QSTAGE(buf, k0) async16(&W[(size_t)(n0 + r) * K + (k0) + cs], &Bs[buf][wid * 512])
        QSTAGE(0, 0);
        QSTAGE(1, BK);
        bf16x8 afX0 = *(const bf16x8*)(Ab);
        bf16x8 afX1 = *(const bf16x8*)(Ab1);
        bf16x8 afY0, afY1;
#define QSTEP(ks, buf, C0, C1, N0, N1, PRE, STG, WAITN)                                      \
    {                                                                                        \
        asm volatile("s_waitcnt vmcnt(" #WAITN ")" ::: "memory");                            \
        __builtin_amdgcn_s_barrier();                                                        \
        const unsigned short* Bsr = Bs[buf];                                                 \
        bf16x8 b0 = *(const bf16x8*)&Bsr[(wn +  0 + l) * BK + xg];                           \
        bf16x8 b1 = *(const bf16x8*)&Bsr[(wn + 16 + l) * BK + xg];                           \
        bf16x8 b2 = *(const bf16x8*)&Bsr[(wn + 32 + l) * BK + xg];                           \
        bf16x8 b3 = *(const bf16x8*)&Bsr[(wn + 48 + l) * BK + xg];                           \
        if (PRE) { N0 = *(const bf16x8*)(Ab  + (size_t)((ks) + 1) * 512);                    \
                   N1 = *(const bf16x8*)(Ab1 + (size_t)((ks) + 1) * 512); }                  \
        acc[0][0] = __builtin_amdgcn_mfma_f32_16x16x32_bf16(C0, b0, acc[0][0], 0, 0, 0);     \
        acc[0][1] = __builtin_amdgcn_mfma_f32_16x16x32_bf16(C0, b1, acc[0][1], 0, 0, 0);     \
        acc[0][2] = __builtin_amdgcn_mfma_f32_16x16x32_bf16(C0, b2, acc[0][2], 0, 0, 0);     \
        acc[0][3] = __builtin_amdgcn_mfma_f32_16x16x32_bf16(C0, b3, acc[0][3], 0, 0, 0);     \
        acc[1][0] = __builtin_amdgcn_mfma_f32_16x16x32_bf16(C1, b0, acc[1][0], 0, 0, 0);     \
        acc[1][1] = __builtin_amdgcn_mfma_f32_16x16x32_bf16(C1, b1, acc[1][1], 0, 0, 0);     \
        acc[1][2] = __builtin_amdgcn_mfma_f32_16x16x32_bf16(C1, b2, acc[1][2], 0, 0, 0);     \
        acc[1][3] = __builtin_amdgcn_mfma_f32_16x16x32_bf16(C1, b3, acc[1][3], 0, 0, 0);     \
        if (STG) QSTAGE(((buf) + 2) & 3, ((ks) + 2) * BK);                                   \
    }
        for (int t = 0; t < 7; ++t) {          // ks = 0..27
            const int k4 = t * 4;
            QSTEP(k4 + 0, 0, afX0, afX1, afY0, afY1, 1, 1, 3)
            QSTEP(k4 + 1, 1, afY0, afY1, afX0, afX1, 1, 1, 3)
            QSTEP(k4 + 2, 2, afX0, afX1, afY0, afY1, 1, 1, 3)
            QSTEP(k4 + 3, 3, afY0, afY1, afX0, afX1, 1, 1, 3)
        }
        QSTEP(28, 0, afX0, afX1, afY0, afY1, 1, 1, 3)      // stages Bs[2] <- ks 30
        QSTEP(29, 1, afY0, afY1, afX0, afX1, 1, 1, 3)      // stages Bs[3] <- ks 31
        QSTEP(30, 2, afX0, afX1, afY0, afY1, 1, 0, 3)      // prefetch A for ks 31
        QSTEP(31, 3, afY0, afY1, afX0, afX1, 0, 0, 0)
#undef QSTEP
#undef QSTAGE
    } else {
        // fallback: fp32 A reg-staged into Bs[2..3] with matching write-side swizzle
        const int cc = (tid & 3);                  // source chunk (A reg-staged path)
        const int sl = (cc ^ ((r >> 1) & 3)) * 8;  // swizzled slot for row r
        auto stageF = [&](int buf, int k0) {
            const float* A = (const float*)Av;
            stage8_f32(&Bs[2 + buf][r * BK + sl], &A[(size_t)(m0 + r) * K + k0 + cc * 8]);
            async16(&W[(size_t)(n0 + r) * K + k0 + cs], &Bs[buf][wid * 512]);
        };
        stageF(0, 0);
        __syncthreads();
        for (int k0 = 0; k0 < K; k0 += BK) {
            const int cur = (k0 >> 5) & 1;
            if (k0 + BK < K) stageF(cur ^ 1, k0 + BK);
            bf16x8 af[2], bfr[4];
#pragma unroll
            for (int im = 0; im < 2; ++im) af[im]  = *(const bf16x8*)&Bs[2 + cur][(wm + im * 16 + l) * BK + xg];
#pragma unroll
            for (int in = 0; in < 4; ++in) bfr[in] = *(const bf16x8*)&Bs[cur][(wn + in * 16 + l) * BK + xg];
#pragma unroll
            for (int im = 0; im < 2; ++im)
#pragma unroll
                for (int in = 0; in < 4; ++in)
                    acc[im][in] = __builtin_amdgcn_mfma_f32_16x16x32_bf16(af[im], bfr[in], acc[im][in], 0, 0, 0);
            __syncthreads();
        }
    }

    unsigned short* outq = outv + (size_t)z * 4194304;
    if (z < 2) {
        const int hq = (n0 + wn) >> 6;               // head (constant per thread)
        float freq[2];
#pragma unroll
        for (int in = 0; in < 2; ++in)
            freq[in] = exp2f(-(float)(in * 16 + l) * 0.41524101186f);  // log2(10000)/32
#pragma unroll
        for (int im = 0; im < 2; ++im)
#pragma unroll
            for (int i = 0; i < 4; ++i) {
                const int m = m0 + wm + im * 16 + g * 4 + i;
                const int b = m >> 11, t = m & 2047;
                float fw = 1.0f;
                if (z == 1) fw = 0.18033688011f * swg[(b << 11) + t];  // SCALE*log2(e)*w
                const size_t fq = (size_t)((b << 4) + hq) * 131072
                                + (size_t)((t >> 5) << 2) * 512
                                + (size_t)((((l >> 3) & 1) << 5) + (t & 31)) * 8 + (l & 7);
#pragma unroll
                for (int in = 0; in < 2; ++in) {
                    const float ang = (float)t * freq[in];
                    const float cs2 = __cosf(ang), sn = __sinf(ang);
                    const float x1 = acc[im][in][i], x2 = acc[im][in + 2][i];
                    outq[fq + (size_t)in * 512]       = f2bf((x1 * cs2 - x2 * sn) * fw);
                    outq[fq + (size_t)(in + 2) * 512] = f2bf((x2 * cs2 + x1 * sn) * fw);
                }
            }
    } else {
        // V fragments: 4 consecutive t -> 4 consecutive slots within one lane group -> ushort4
#pragma unroll
        for (int im = 0; im < 2; ++im)
#pragma unroll
            for (int in = 0; in < 4; ++in) {
                const int n = n0 + wn + in * 16 + l;
                const int h = n >> 6, d = n & 63;
                const int mb = m0 + wm + im * 16 + g * 4;
                const int bq = mb >> 11, t0 = mb & 2047;
                ushort4 pk;
                pk.x = f2bf(acc[im][in][0]); pk.y = f2bf(acc[im][in][1]);
                pk.z = f2bf(acc[im][in][2]); pk.w = f2bf(acc[im][in][3]);
                const size_t fv = (size_t)((bq << 4) + h) * 131072
                                + (size_t)(((t0 >> 5) << 2) + ((d >> 5) << 1) + ((t0 >> 4) & 1)) * 512
                                + (size_t)((((t0 >> 3) & 1) << 5) + (d & 31)) * 8 + (t0 & 7);
                *(ushort4*)&outq[fv] = pk;
            }
    }
}

// Projection v2 (r13-exact): C = A(bf16 row-major)[4096,1024] x Wo^T + bias, 64x128
// tile -> 512 blocks of 512 threads / 8 waves. Wave tile 32x32. Asymmetric staging:
// waves 0-3 load A+B, waves 4-7 B only -> per-wave counted vmcnt(2)/vmcnt(1).
__global__ __launch_bounds__(512) void gemm_proj(
    const unsigned short* __restrict__ A, const unsigned short* __restrict__ W,
    float* __restrict__ out, const float* __restrict__ bias)
{
    constexpr int K = 1024, BK = 32, NS = K / BK;
    __shared__ __align__(16) unsigned short As[3][64 * BK];
    __shared__ __align__(16) unsigned short Bs[3][128 * BK];
    const int tid = threadIdx.x;
    const int wid = tid >> 6, lane = tid & 63, g = lane >> 4, l = lane & 15;
    const int wm = (wid & 1) * 32, wn = (wid >> 1) * 32;

    const int lin = blockIdx.x + (blockIdx.y << 3);     // 512 blocks, 512%8==0
    const int wg  = (lin & 7) * 64 + (lin >> 3);
    const int m0 = (wg >> 3) * 64, n0 = (wg & 7) * 128;

    f32x4 acc[2][2];
#pragma unroll
    for (int i = 0; i < 2; ++i)
#pragma unroll
        for (int j = 0; j < 2; ++j) acc[i][j] = f32x4{0.f, 0.f, 0.f, 0.f};

    const int r  = tid >> 2;                              // B row 0..127; A row 0..63 (tid<256)
    const int cs = (((tid & 3) ^ ((tid >> 3) & 3)) * 8);
    const int xg = (g ^ ((l >> 1) & 3)) * 8;

    auto stage = [&](int buf, int k0) {
        if (tid < 256) async16(&A[(size_t)(m0 + r) * K + k0 + cs], &As[buf][wid * 512]);
        async16(&W[(size_t)(n0 + r) * K + k0 + cs], &Bs[buf][wid * 512]);
    };
    auto compute = [&](int buf) {
        const unsigned short* Asr = As[buf];
        const unsigned short* Bsr = Bs[buf];
        bf16x8 af[2], bfr[2];
#pragma unroll
        for (int im = 0; im < 2; ++im) af[im]  = *(const bf16x8*)&Asr[(wm + im * 16 + l) * BK + xg];
#pragma unroll
        for (int in = 0; in < 2; ++in) bfr[in] = *(const bf16x8*)&Bsr[(wn + in * 16 + l) * BK + xg];
#pragma unroll
        for (int im = 0; im < 2; ++im)
#pragma unroll
            for (int in = 0; in < 2; ++in)
                acc[im][in] = __builtin_amdgcn_mfma_f32_16x16x32_bf16(af[im], bfr[in], acc[im][in], 0, 0, 0);
    };

    stage(0, 0);
    stage(1, BK);
    for (int ks = 0; ks < NS; ++ks) {
        if (ks + 1 < NS) {
            if (wid < 4) asm volatile("s_waitcnt vmcnt(2)" ::: "memory");
            else         asm volatile("s_waitcnt vmcnt(1)" ::: "memory");
        } else {
            asm volatile("s_waitcnt vmcnt(0)" ::: "memory");
        }
        __builtin_amdgcn_s_barrier();
        compute(ks % 3);
        if (ks + 2 < NS) stage((ks + 2) % 3, (ks + 2) * BK);
    }

#pragma unroll
    for (int im = 0; im < 2; ++im)
#pragma unroll
        for (int in = 0; in < 2; ++in) {
            const int n = n0 + wn + in * 16 + l;
#pragma unroll
            for (int i = 0; i < 4; ++i) {
                const int m = m0 + wm + im * 16 + g * 4 + i;
                out[(size_t)m * 1024 + n] = acc[im][in][i] + bias[n];
            }
        }
}

// Flash v7s: 2048 blocks x 128 threads, block = (bh, 32q strip p), longest-first.
// r13's v7 + setprio(1) around the two MFMA clusters (T5; only change this round).
// No LDS staging, barrier-free loop, K one-chunk-ahead register prefetch. Swapped QK^T
// -> in-register softmax (16 exp2 + 8 cvt_pk + 4 permlane32_swap). K pre-scaled by
// SCALE*log2e*w[key]. Constant-max softmax -> 2-wave additive combine.
__global__ __launch_bounds__(128, 2) void flash_attn(
    const unsigned short* __restrict__ Qf, const unsigned short* __restrict__ Kf,
    const unsigned short* __restrict__ Vf, const float* __restrict__ sbias,
    const float* __restrict__ sw, unsigned short* __restrict__ attn)
{
    constexpr int T = 2048;
    __shared__ float Cmb[3072];             // 2x16x64 oacc + 16x64 lrow = 12 KB

    const int tid = threadIdx.x, wid = tid >> 6, lane = tid & 63;
    const int hl = lane & 31, hh = lane >> 5;
    const int id = blockIdx.x;
    const int p  = 63 - (id >> 5);          // globally longest-first
    const int bh = id & 31, b = bh >> 4, h = bh & 15;
    const size_t fb = (size_t)bh * 131072;  // fragment base (Q/K/V identical shape)
    const float bias = sbias[h];
    const float* swb = sw + b * T;

    bf16x8 onef;
#pragma unroll
    for (int j = 0; j < 8; ++j) onef[j] = (__bf16)1.0f;

    const int q0 = p * 32;
    bf16x8 qf[4];
#pragma unroll
    for (int ks = 0; ks < 4; ++ks)
        qf[ks] = *(const bf16x8*)&Qf[fb + (size_t)(p * 4 + ks) * 512 + lane * 8];

    f32x16 oacc[2], lrow;
#pragma unroll
    for (int r = 0; r < 16; ++r) { oacc[0][r] = 0.f; oacc[1][r] = 0.f; lrow[r] = 0.f; }

    // prologue: load K for this wave's first chunk
    bf16x8 kcur[4];
    if (wid <= p) {
        const unsigned short* kb = &Kf[fb + (size_t)wid * 2048 + lane * 8];
#pragma unroll
        for (int ks = 0; ks < 4; ++ks) kcur[ks] = *(const bf16x8*)&kb[ks * 512];
    }

    for (int c = wid; c <= p; c += 2) {
        // S^T = K' Q^T (32k x 32q): lane holds q = q0+hl, rows r -> keys
        f32x16 sx;
#pragma unroll
        for (int r = 0; r < 16; ++r) sx[r] = 0.f;
        __builtin_amdgcn_s_setprio(1);
        sx = __builtin_amdgcn_mfma_f32_32x32x16_bf16(kcur[0], qf[0], sx, 0, 0, 0);
        sx = __builtin_amdgcn_mfma_f32_32x32x16_bf16(kcur[1], qf[1], sx, 0, 0, 0);
        sx = __builtin_amdgcn_mfma_f32_32x32x16_bf16(kcur[2], qf[2], sx, 0, 0, 0);
        sx = __builtin_amdgcn_mfma_f32_32x32x16_bf16(kcur[3], qf[3], sx, 0, 0, 0);
        __builtin_amdgcn_s_setprio(0);

        // prefetch next chunk's K (kcur regs dead after the MFMAs above)
        if (c + 2 <= p) {
            const unsigned short* kb = &Kf[fb + (size_t)(c + 2) * 2048 + lane * 8];
#pragma unroll
            for (int ks = 0; ks < 4; ++ks) kcur[ks] = *(const bf16x8*)&kb[ks * 512];
        }

        // issue V loads now; softmax below covers their L2 latency
        const unsigned short* vb = &Vf[fb + (size_t)c * 2048 + lane * 8];
        const bf16x8 vf00 = *(const bf16x8*)&vb[0];      // (dt0,ks0)
        const bf16x8 vf01 = *(const bf16x8*)&vb[512];    // (dt0,ks1)
        const bf16x8 vf10 = *(const bf16x8*)&vb[1024];   // (dt1,ks0)
        const bf16x8 vf11 = *(const bf16x8*)&vb[1536];   // (dt1,ks1)

        if (bias != 0.0f) {                  // benchmark has sector_bias == 0
            const float bn = bias * 1.44269504f;
#pragma unroll
            for (int r = 0; r < 16; ++r) {
                const int kl = (r & 3) + 8 * (r >> 2) + 4 * hh;
                sx[r] += bn * swb[c * 32 + kl];
            }
        }
        if (c == p) {                        // diagonal chunk: causal mask (key kl <= q hl)
#pragma unroll
            for (int r = 0; r < 16; ++r) {
                const int kl = (r & 3) + 8 * (r >> 2) + 4 * hh;
                sx[r] = (kl <= hl) ? sx[r] : -1e30f;
            }
        }
#pragma unroll
        for (int r = 0; r < 16; ++r) sx[r] = exp2f(sx[r]);

        // pack P -> bf16 A-fragment: 8 cvt_pk + 4 permlane32_swap
        unsigned wds[8];
#pragma unroll
        for (int g2 = 0; g2 < 4; ++g2) {
            wds[g2 * 2]     = cvtpk(sx[g2 * 4],     sx[g2 * 4 + 1]);
            wds[g2 * 2 + 1] = cvtpk(sx[g2 * 4 + 2], sx[g2 * 4 + 3]);
        }
        bf16x8 pf[2];
#pragma unroll
        for (int ks = 0; ks < 2; ++ks) {
            unsigned a0, a1, b0, b1;
            plswap(wds[4 * ks],     wds[4 * ks + 2], a0, a1);
            plswap(wds[4 * ks + 1], wds[4 * ks + 3], b0, b1);
            union { unsigned u[4]; bf16x8 v; } pk_;
            pk_.u[0] = a0; pk_.u[1] = b0;
            pk_.u[2] = a1; pk_.u[3] = b1;
            pf[ks] = pk_.v;
        }

        // rowsum via ones-MFMA + O += P V
        __builtin_amdgcn_s_setprio(1);
        lrow = __builtin_amdgcn_mfma_f32_32x32x16_bf16(pf[0], onef, lrow, 0, 0, 0);
        lrow = __builtin_amdgcn_mfma_f32_32x32x16_bf16(pf[1], onef, lrow, 0, 0, 0);
        oacc[0] = __builtin_amdgcn_mfma_f32_32x32x16_bf16(pf[0], vf00, oacc[0], 0, 0, 0);
        oacc[0] = __builtin_amdgcn_mfma_f32_32x32x16_bf16(pf[1], vf01, oacc[0], 0, 0, 0);
        oacc[1] = __builtin_amdgcn_mfma_f32_32x32x16_bf16(pf[0], vf10, oacc[1], 0, 0, 0);
        oacc[1] = __builtin_amdgcn_mfma_f32_32x32x16_bf16(pf[1], vf11, oacc[1], 0, 0, 0);
        __builtin_amdgcn_s_setprio(0);
    }

    // combine the two waves' partials (additive under constant-max softmax)
    __syncthreads();
    if (wid == 1) {
#pragma unroll
        for (int dt = 0; dt < 2; ++dt)
#pragma unroll
            for (int r = 0; r < 16; ++r) Cmb[(dt * 16 + r) * 64 + lane] = oacc[dt][r];
#pragma unroll
        for (int r = 0; r < 16; ++r) Cmb[2048 + r * 64 + lane] = lrow[r];
    }
    __syncthreads();
    if (wid == 0) {
#pragma unroll
        for (int r = 0; r < 16; ++r) {
            const float li = 1.0f / (lrow[r] + Cmb[2048 + r * 64 + lane]);
            const int row = (r & 3) + 8 * (r >> 2) + 4 * hh;
            const int qr = q0 + row;
#pragma unroll
            for (int dt = 0; dt < 2; ++dt) {
                const float ov = oacc[dt][r] + Cmb[(dt * 16 + r) * 64 + lane];
                attn[(size_t)(b * T + qr) * 1024 + h * 64 + dt * 32 + hl] = f2bf(ov * li);
            }
        }
    }
}

extern "C" void kernel_launch(void* const* d_in, const int* in_sizes, int n_in,
                              void* d_out, int out_size, void* d_ws, size_t ws_size,
                              hipStream_t stream) {
    const float* x  = (const float*)d_in[0];
    const float* Wq = (const float*)d_in[1];
    const float* Wk = (const float*)d_in[2];
    const float* Wv = (const float*)d_in[3];
    const float* Wo = (const float*)d_in[4];
    const float* bo = (const float*)d_in[5];
    const float* sb = (const float*)d_in[6];
    const float* sw = (const float*)d_in[7];

    const size_t QKV_SZ = 4194304;   // shorts per q/k/v tensor
    const size_t W_SZ   = 1048576;   // shorts per weight matrix
    unsigned short* ws16 = (unsigned short*)d_ws;
    const bool big = ws_size >= 2 * (4 * QKV_SZ + 4 * W_SZ);  // 41.9 MB

    if (big) {
        unsigned short* xb    = ws16;            // x (A-fragment-major)
        unsigned short* Wb3   = xb + QKV_SZ;     // Wq,Wk,Wv (row-major)
        unsigned short* Wob   = Wb3 + 3 * W_SZ;  // Wo (row-major)
        unsigned short* qkv   = Wob + W_SZ;      // q,k,v (flash-fragment-major)
        unsigned short* attnb = xb;              // overlay x (dead after QKV gemm)

        cvt_all<<<4096, 256, 0, stream>>>(x, Wq, Wk, Wv, Wo, xb, 1, 1048576);
        gemm_qkv<1><<<dim3(8, 32, 3), 512, 0, stream>>>(xb, Wb3, qkv, sw);
        flash_attn<<<2048, 128, 0, stream>>>(qkv, qkv + QKV_SZ, qkv + 2 * QKV_SZ,
                                             sb, sw, attnb);
        gemm_proj<<<dim3(8, 64), 512, 0, stream>>>(attnb, Wob, (float*)d_out, bo);
    } else {                                     // 33.6 MB fallback
        unsigned short* qkv   = ws16;
        unsigned short* attnb = qkv + 3 * QKV_SZ;
        unsigned short* Wb3   = attnb;           // overlay attn (dead until flash)
        unsigned short* Wob   = qkv;             // overlay q (dead after flash)

        cvt_all<<<1536, 256, 0, stream>>>(x, Wq, Wk, Wv, Wo, Wb3, 0, 393216);
        gemm_qkv<0><<<dim3(8, 32, 3), 512, 0, stream>>>(x, Wb3, qkv, sw);
        flash_attn<<<2048, 128, 0, stream>>>(qkv, qkv + QKV_SZ, qkv + 2 * QKV_SZ,
                                             sb, sw, attnb);
        cvt_all<<<512, 256, 0, stream>>>(x, Wo, Wo, Wo, Wo, Wob, 0, 131072);
        gemm_proj<<<dim3(8, 64), 512, 0, stream>>>(attnb, Wob, (float*)d_out, bo);
    }
}

// Round 16
// 180.307 us; speedup vs baseline: 1.0315x; 1.0067x over previous
//
#include <hip/hip_runtime.h>

// QuantFinanceAttention: B=2, T=2048, C=1024, H=16, dk=64. fp32 I/O, bf16 MFMA internals.
// cvt(x -> A-FRAGMENT-major, weights row-major) | QKV gemm v6b: HYBRID feed -- A-frags
// streamed from L2 (frag-major, named-register ping-pong + macro unroll; lambda-pointer
// version alloca'd -> scratch vmem polluted counted vmcnt -> NaN [r12, rule #20]);
// B via 4-buffer LDS, counted vmcnt(3) | flash v7: no LDS staging, barrier-free loop,
// K one-chunk-ahead register prefetch, in-register softmax (swapped QK^T, cvt_pk +
// permlane32_swap), K pre-scaled by SCALE*log2e*sector_w, constant-max softmax ->
// 2-wave additive combine | proj v2: 512-thr/8-wave, asymmetric counted vmcnt.
// FINAL (r16 = r13-exact revert): session 224.7 -> 180.5 us. Tested and rejected:
// 4-wave flash key-split (r14, -5.5us), setprio on flash (r15, -1us), no-LDS GEMM
// (r8, B needs LDS reuse), bank-conflict fixes at low occupancy (r7/r10, neutral --
// not the critical path). Remaining state is a latency-bound local minimum with all
// pipes <50%; further gains need structural fusion, repeatedly net-negative here.

typedef __bf16 bf16x8 __attribute__((ext_vector_type(8)));
typedef float f32x4 __attribute__((ext_vector_type(4)));
typedef float f32x16 __attribute__((ext_vector_type(16)));
typedef unsigned short u16x8 __attribute__((ext_vector_type(8)));

__device__ __forceinline__ unsigned short f2bf(float f) {
    union { float f; unsigned int u; } c; c.f = f;
    unsigned int u = c.u;
    unsigned int r = u + 0x7fffu + ((u >> 16) & 1u);  // RNE
    return (unsigned short)(r >> 16);
}
__device__ __forceinline__ unsigned cvtpk(float lo, float hi) {
    unsigned r;
    asm("v_cvt_pk_bf16_f32 %0, %1, %2" : "=v"(r) : "v"(lo), "v"(hi));
    return r;
}
// Exchange across the lane<32 / lane>=32 halves:
//   ret0[l<32]=a[l], ret0[l>=32]=b[l-32];  ret1[l<32]=a[l+32], ret1[l>=32]=b[l]
__device__ __forceinline__ void plswap(unsigned a, unsigned b, unsigned& r0, unsigned& r1) {
#if __has_builtin(__builtin_amdgcn_permlane32_swap)
    auto s = __builtin_amdgcn_permlane32_swap(a, b, false, false);
    r0 = (unsigned)s[0]; r1 = (unsigned)s[1];
#else
    const int hh = (int)(threadIdx.x & 63) >> 5;
    const unsigned oa = (unsigned)__shfl_xor((int)a, 32);
    const unsigned ob = (unsigned)__shfl_xor((int)b, 32);
    r0 = hh ? ob : a;
    r1 = hh ? b : oa;
#endif
}
__device__ __forceinline__ void stage8_f32(unsigned short* dst, const float* src) {
    const float4 a = *(const float4*)src;
    const float4 b = *(const float4*)(src + 4);
    u16x8 v;
    v[0] = f2bf(a.x); v[1] = f2bf(a.y); v[2] = f2bf(a.z); v[3] = f2bf(a.w);
    v[4] = f2bf(b.x); v[5] = f2bf(b.y); v[6] = f2bf(b.z); v[7] = f2bf(b.w);
    *(u16x8*)dst = v;
}
__device__ __forceinline__ void async16(const unsigned short* g, unsigned short* l) {
    __builtin_amdgcn_global_load_lds(
        (const __attribute__((address_space(1))) void*)g,
        (__attribute__((address_space(3))) void*)l, 16, 0, 0);
}

// A-fragment-major layout (shorts) for a [R][1024] bf16 matrix:
//   addr(row, k) = (row>>4)*16384 + (k>>5)*512 + ((k>>3)&3)*128 + (row&15)*8 + (k&7)
__global__ __launch_bounds__(256) void cvt_all(
    const float* __restrict__ x, const float* __restrict__ Wq, const float* __restrict__ Wk,
    const float* __restrict__ Wv, const float* __restrict__ Wo,
    unsigned short* __restrict__ dst, int hasX, int n8)
{
    const int i = blockIdx.x * 256 + threadIdx.x;
    if (i >= n8) return;
    int r = i;
    const float* src; size_t soff;
    const int xg = hasX ? 524288 : 0;
    if (r < xg) {                            // x -> A-fragment-major (big path only)
        const int lane16 = r & 15, sub = (r >> 4) & 3, kb = (r >> 6) & 31, rb = r >> 11;
        src = x; soff = (size_t)(rb * 16 + lane16) * 128 + kb * 4 + sub;
    } else {
        r -= xg;
        const int w = r >> 17, o = r & 131071;
        src = (w == 0) ? Wq : (w == 1) ? Wk : (w == 2) ? Wv : Wo;
        soff = o;                            // weights: row-major
    }
    stage8_f32(&dst[(size_t)i * 8], &src[soff * 8]);
}

// Flash fragment layouts (per bh = 131072 shorts), written by the qkv epilogue:
//  Q/K: addr = bh*131072 + ((t>>5)*4 + (d>>4))*512 + (((d>>3)&1)*32 + (t&31))*8 + (d&7)
//  V:   addr = bh*131072 + ((t>>5)*4 + (d>>5)*2 + ((t>>4)&1))*512 + (((t>>3)&1)*32 + (d&31))*8 + (t&7)
template<int A_BF16>
__global__ __launch_bounds__(512) void gemm_qkv(
    const void* __restrict__ Av, const unsigned short* __restrict__ Wb,
    unsigned short* __restrict__ outv, const float* __restrict__ swg)
{
    constexpr int K = 1024, BK = 32;
    __shared__ __align__(16) unsigned short Bs[4][128 * BK];   // 32KB (fallback: 2,3 = As)
    const int tid = threadIdx.x;
    const int wid = tid >> 6, lane = tid & 63, g = lane >> 4, l = lane & 15;
    const int wm = (wid & 3) * 32, wn = (wid >> 2) * 64;

    // XCD-chunked bijective swizzle (768 blocks, 768%8==0)
    const int lin = blockIdx.x + (blockIdx.y << 3) + (blockIdx.z << 8);
    const int wg  = (lin & 7) * 96 + (lin >> 3);
    const int bx = wg & 7, by = (wg >> 3) & 31, bz = wg >> 8;
    const int m0 = by * 128, n0 = bx * 128;
    const int z = bz;
    const unsigned short* W = Wb + (size_t)z * 1048576;

    f32x4 acc[2][4];
#pragma unroll
    for (int i = 0; i < 2; ++i)
#pragma unroll
        for (int j = 0; j < 4; ++j) acc[i][j] = f32x4{0.f, 0.f, 0.f, 0.f};

    const int r  = tid >> 2;                              // staged row 0..127
    const int cs = (((tid & 3) ^ ((tid >> 3) & 3)) * 8);  // pre-swizzled source chunk
    const int xg = (g ^ ((l >> 1) & 3)) * 8;              // read-side chunk

    if (A_BF16) {
        const unsigned short* Ab = (const unsigned short*)Av;
        Ab += (size_t)((m0 + wm) >> 4) * 16384 + g * 128 + l * 8;
        const unsigned short* Ab1 = Ab + 16384;
#define QSTAGE(buf, k0) async16(&W[(size_t)(n0 + r) * K + (k0) + cs], &Bs[buf][wid * 512])
        QSTAGE(0, 0);
        QSTAGE(1, BK);
        bf16x8 afX0 = *(const bf16x8*)(Ab);
        bf16x8 afX1 = *(const bf16x8*)(Ab1);
        bf16x8 afY0, afY1;
// Named-register step: no arrays, no pointer params -> no alloca/scratch (rule #20),
// so the vmcnt(3) count (3 loads/body: 2 A-frag + 1 B-stage) stays exact.
#define QSTEP(ks, buf, C0, C1, N0, N1, PRE, STG, WAITN)                                      \
    {                                                                                        \
        asm volatile("s_waitcnt vmcnt(" #WAITN ")" ::: "memory");                            \
        __builtin_amdgcn_s_barrier();                                                        \
        const unsigned short* Bsr = Bs[buf];                                                 \
        bf16x8 b0 = *(const bf16x8*)&Bsr[(wn +  0 + l) * BK + xg];                           \
        bf16x8 b1 = *(const bf16x8*)&Bsr[(wn + 16 + l) * BK + xg];                           \
        bf16x8 b2 = *(const bf16x8*)&Bsr[(wn + 32 + l) * BK + xg];                           \
        bf16x8 b3 = *(const bf16x8*)&Bsr[(wn + 48 + l) * BK + xg];                           \
        if (PRE) { N0 = *(const bf16x8*)(Ab  + (size_t)((ks) + 1) * 512);                    \
                   N1 = *(const bf16x8*)(Ab1 + (size_t)((ks) + 1) * 512); }                  \
        acc[0][0] = __builtin_amdgcn_mfma_f32_16x16x32_bf16(C0, b0, acc[0][0], 0, 0, 0);     \
        acc[0][1] = __builtin_amdgcn_mfma_f32_16x16x32_bf16(C0, b1, acc[0][1], 0, 0, 0);     \
        acc[0][2] = __builtin_amdgcn_mfma_f32_16x16x32_bf16(C0, b2, acc[0][2], 0, 0, 0);     \
        acc[0][3] = __builtin_amdgcn_mfma_f32_16x16x32_bf16(C0, b3, acc[0][3], 0, 0, 0);     \
        acc[1][0] = __builtin_amdgcn_mfma_f32_16x16x32_bf16(C1, b0, acc[1][0], 0, 0, 0);     \
        acc[1][1] = __builtin_amdgcn_mfma_f32_16x16x32_bf16(C1, b1, acc[1][1], 0, 0, 0);     \
        acc[1][2] = __builtin_amdgcn_mfma_f32_16x16x32_bf16(C1, b2, acc[1][2], 0, 0, 0);     \
        acc[1][3] = __builtin_amdgcn_mfma_f32_16x16x32_bf16(C1, b3, acc[1][3], 0, 0, 0);     \
        if (STG) QSTAGE(((buf) + 2) & 3, ((ks) + 2) * BK);                                   \
    }
        for (int t = 0; t < 7; ++t) {          // ks = 0..27
            const int k4 = t * 4;
            QSTEP(k4 + 0, 0, afX0, afX1, afY0, afY1, 1, 1, 3)
            QSTEP(k4 + 1, 1, afY0, afY1, afX0, afX1, 1, 1, 3)
            QSTEP(k4 + 2, 2, afX0, afX1, afY0, afY1, 1, 1, 3)
            QSTEP(k4 + 3, 3, afY0, afY1, afX0, afX1, 1, 1, 3)
        }
        QSTEP(28, 0, afX0, afX1, afY0, afY1, 1, 1, 3)      // stages Bs[2] <- ks 30
        QSTEP(29, 1, afY0, afY1, afX0, afX1, 1, 1, 3)      // stages Bs[3] <- ks 31
        QSTEP(30, 2, afX0, afX1, afY0, afY1, 1, 0, 3)      // prefetch A for ks 31
        QSTEP(31, 3, afY0, afY1, afX0, afX1, 0, 0, 0)
#undef QSTEP
#undef QSTAGE
    } else {
        // fallback: fp32 A reg-staged into Bs[2..3] with matching write-side swizzle
        const int cc = (tid & 3);                  // source chunk (A reg-staged path)
        const int sl = (cc ^ ((r >> 1) & 3)) * 8;  // swizzled slot for row r
        auto stageF = [&](int buf, int k0) {
            const float* A = (const float*)Av;
            stage8_f32(&Bs[2 + buf][r * BK + sl], &A[(size_t)(m0 + r) * K + k0 + cc * 8]);
            async16(&W[(size_t)(n0 + r) * K + k0 + cs], &Bs[buf][wid * 512]);
        };
        stageF(0, 0);
        __syncthreads();
        for (int k0 = 0; k0 < K; k0 += BK) {
            const int cur = (k0 >> 5) & 1;
            if (k0 + BK < K) stageF(cur ^ 1, k0 + BK);
            bf16x8 af[2], bfr[4];
#pragma unroll
            for (int im = 0; im < 2; ++im) af[im]  = *(const bf16x8*)&Bs[2 + cur][(wm + im * 16 + l) * BK + xg];
#pragma unroll
            for (int in = 0; in < 4; ++in) bfr[in] = *(const bf16x8*)&Bs[cur][(wn + in * 16 + l) * BK + xg];
#pragma unroll
            for (int im = 0; im < 2; ++im)
#pragma unroll
                for (int in = 0; in < 4; ++in)
                    acc[im][in] = __builtin_amdgcn_mfma_f32_16x16x32_bf16(af[im], bfr[in], acc[im][in], 0, 0, 0);
            __syncthreads();
        }
    }

    unsigned short* outq = outv + (size_t)z * 4194304;
    if (z < 2) {
        const int hq = (n0 + wn) >> 6;               // head (constant per thread)
        float freq[2];
#pragma unroll
        for (int in = 0; in < 2; ++in)
            freq[in] = exp2f(-(float)(in * 16 + l) * 0.41524101186f);  // log2(10000)/32
#pragma unroll
        for (int im = 0; im < 2; ++im)
#pragma unroll
            for (int i = 0; i < 4; ++i) {
                const int m = m0 + wm + im * 16 + g * 4 + i;
                const int b = m >> 11, t = m & 2047;
                float fw = 1.0f;
                if (z == 1) fw = 0.18033688011f * swg[(b << 11) + t];  // SCALE*log2(e)*w
                const size_t fq = (size_t)((b << 4) + hq) * 131072
                                + (size_t)((t >> 5) << 2) * 512
                                + (size_t)((((l >> 3) & 1) << 5) + (t & 31)) * 8 + (l & 7);
#pragma unroll
                for (int in = 0; in < 2; ++in) {
                    const float ang = (float)t * freq[in];
                    const float cs2 = __cosf(ang), sn = __sinf(ang);
                    const float x1 = acc[im][in][i], x2 = acc[im][in + 2][i];
                    outq[fq + (size_t)in * 512]       = f2bf((x1 * cs2 - x2 * sn) * fw);
                    outq[fq + (size_t)(in + 2) * 512] = f2bf((x2 * cs2 + x1 * sn) * fw);
                }
            }
    } else {
        // V fragments: 4 consecutive t -> 4 consecutive slots within one lane group -> ushort4
#pragma unroll
        for (int im = 0; im < 2; ++im)
#pragma unroll
            for (int in = 0; in < 4; ++in) {
                const int n = n0 + wn + in * 16 + l;
                const int h = n >> 6, d = n & 63;
                const int mb = m0 + wm + im * 16 + g * 4;
                const int bq = mb >> 11, t0 = mb & 2047;
                ushort4 pk;
                pk.x = f2bf(acc[im][in][0]); pk.y = f2bf(acc[im][in][1]);
                pk.z = f2bf(acc[im][in][2]); pk.w = f2bf(acc[im][in][3]);
                const size_t fv = (size_t)((bq << 4) + h) * 131072
                                + (size_t)(((t0 >> 5) << 2) + ((d >> 5) << 1) + ((t0 >> 4) & 1)) * 512
                                + (size_t)((((t0 >> 3) & 1) << 5) + (d & 31)) * 8 + (t0 & 7);
                *(ushort4*)&outq[fv] = pk;
            }
    }
}

// Projection v2: C = A(bf16 row-major)[4096,1024] x Wo^T + bias, 64x128 tile ->
// 512 blocks of 512 threads / 8 waves. Wave tile 32x32. Asymmetric staging:
// waves 0-3 load A+B, waves 4-7 B only -> per-wave counted vmcnt(2)/vmcnt(1).
__global__ __launch_bounds__(512) void gemm_proj(
    const unsigned short* __restrict__ A, const unsigned short* __restrict__ W,
    float* __restrict__ out, const float* __restrict__ bias)
{
    constexpr int K = 1024, BK = 32, NS = K / BK;
    __shared__ __align__(16) unsigned short As[3][64 * BK];
    __shared__ __align__(16) unsigned short Bs[3][128 * BK];
    const int tid = threadIdx.x;
    const int wid = tid >> 6, lane = tid & 63, g = lane >> 4, l = lane & 15;
    const int wm = (wid & 1) * 32, wn = (wid >> 1) * 32;

    const int lin = blockIdx.x + (blockIdx.y << 3);     // 512 blocks, 512%8==0
    const int wg  = (lin & 7) * 64 + (lin >> 3);
    const int m0 = (wg >> 3) * 64, n0 = (wg & 7) * 128;

    f32x4 acc[2][2];
#pragma unroll
    for (int i = 0; i < 2; ++i)
#pragma unroll
        for (int j = 0; j < 2; ++j) acc[i][j] = f32x4{0.f, 0.f, 0.f, 0.f};

    const int r  = tid >> 2;                              // B row 0..127; A row 0..63 (tid<256)
    const int cs = (((tid & 3) ^ ((tid >> 3) & 3)) * 8);
    const int xg = (g ^ ((l >> 1) & 3)) * 8;

    auto stage = [&](int buf, int k0) {
        if (tid < 256) async16(&A[(size_t)(m0 + r) * K + k0 + cs], &As[buf][wid * 512]);
        async16(&W[(size_t)(n0 + r) * K + k0 + cs], &Bs[buf][wid * 512]);
    };
    auto compute = [&](int buf) {
        const unsigned short* Asr = As[buf];
        const unsigned short* Bsr = Bs[buf];
        bf16x8 af[2], bfr[2];
#pragma unroll
        for (int im = 0; im < 2; ++im) af[im]  = *(const bf16x8*)&Asr[(wm + im * 16 + l) * BK + xg];
#pragma unroll
        for (int in = 0; in < 2; ++in) bfr[in] = *(const bf16x8*)&Bsr[(wn + in * 16 + l) * BK + xg];
#pragma unroll
        for (int im = 0; im < 2; ++im)
#pragma unroll
            for (int in = 0; in < 2; ++in)
                acc[im][in] = __builtin_amdgcn_mfma_f32_16x16x32_bf16(af[im], bfr[in], acc[im][in], 0, 0, 0);
    };

    stage(0, 0);
    stage(1, BK);
    for (int ks = 0; ks < NS; ++ks) {
        if (ks + 1 < NS) {
            if (wid < 4) asm volatile("s_waitcnt vmcnt(2)" ::: "memory");
            else         asm volatile("s_waitcnt vmcnt(1)" ::: "memory");
        } else {
            asm volatile("s_waitcnt vmcnt(0)" ::: "memory");
        }
        __builtin_amdgcn_s_barrier();
        compute(ks % 3);
        if (ks + 2 < NS) stage((ks + 2) % 3, (ks + 2) * BK);
    }

#pragma unroll
    for (int im = 0; im < 2; ++im)
#pragma unroll
        for (int in = 0; in < 2; ++in) {
            const int n = n0 + wn + in * 16 + l;
#pragma unroll
            for (int i = 0; i < 4; ++i) {
                const int m = m0 + wm + im * 16 + g * 4 + i;
                out[(size_t)m * 1024 + n] = acc[im][in][i] + bias[n];
            }
        }
}

// Flash v7: 2048 blocks x 128 threads, block = (bh, 32q strip p), longest-first.
// No LDS staging, barrier-free loop, K one-chunk-ahead register prefetch. Swapped QK^T
// -> in-register softmax (16 exp2 + 8 cvt_pk + 4 permlane32_swap). K pre-scaled by
// SCALE*log2e*w[key]. Constant-max softmax -> 2-wave additive combine.
__global__ __launch_bounds__(128, 2) void flash_attn(
    const unsigned short* __restrict__ Qf, const unsigned short* __restrict__ Kf,
    const unsigned short* __restrict__ Vf, const float* __restrict__ sbias,
    const float* __restrict__ sw, unsigned short* __restrict__ attn)
{
    constexpr int T = 2048;
    __shared__ float Cmb[3072];             // 2x16x64 oacc + 16x64 lrow = 12 KB

    const int tid = threadIdx.x, wid = tid >> 6, lane = tid & 63;
    const int hl = lane & 31, hh = lane >> 5;
    const int id = blockIdx.x;
    const int p  = 63 - (id >> 5);          // globally longest-first
    const int bh = id & 31, b = bh >> 4, h = bh & 15;
    const size_t fb = (size_t)bh * 131072;  // fragment base (Q/K/V identical shape)
    const float bias = sbias[h];
    const float* swb = sw + b * T;

    bf16x8 onef;
#pragma unroll
    for (int j = 0; j < 8; ++j) onef[j] = (__bf16)1.0f;

    const int q0 = p * 32;
    bf16x8 qf[4];
#pragma unroll
    for (int ks = 0; ks < 4; ++ks)
        qf[ks] = *(const bf16x8*)&Qf[fb + (size_t)(p * 4 + ks) * 512 + lane * 8];

    f32x16 oacc[2], lrow;
#pragma unroll
    for (int r = 0; r < 16; ++r) { oacc[0][r] = 0.f; oacc[1][r] = 0.f; lrow[r] = 0.f; }

    // prologue: load K for this wave's first chunk
    bf16x8 kcur[4];
    if (wid <= p) {
        const unsigned short* kb = &Kf[fb + (size_t)wid * 2048 + lane * 8];
#pragma unroll
        for (int ks = 0; ks < 4; ++ks) kcur[ks] = *(const bf16x8*)&kb[ks * 512];
    }

    for (int c = wid; c <= p; c += 2) {
        // S^T = K' Q^T (32k x 32q): lane holds q = q0+hl, rows r -> keys
        f32x16 sx;
#pragma unroll
        for (int r = 0; r < 16; ++r) sx[r] = 0.f;
        sx = __builtin_amdgcn_mfma_f32_32x32x16_bf16(kcur[0], qf[0], sx, 0, 0, 0);
        sx = __builtin_amdgcn_mfma_f32_32x32x16_bf16(kcur[1], qf[1], sx, 0, 0, 0);
        sx = __builtin_amdgcn_mfma_f32_32x32x16_bf16(kcur[2], qf[2], sx, 0, 0, 0);
        sx = __builtin_amdgcn_mfma_f32_32x32x16_bf16(kcur[3], qf[3], sx, 0, 0, 0);

        // prefetch next chunk's K (kcur regs dead after the MFMAs above)
        if (c + 2 <= p) {
            const unsigned short* kb = &Kf[fb + (size_t)(c + 2) * 2048 + lane * 8];
#pragma unroll
            for (int ks = 0; ks < 4; ++ks) kcur[ks] = *(const bf16x8*)&kb[ks * 512];
        }

        // issue V loads now; softmax below covers their L2 latency
        const unsigned short* vb = &Vf[fb + (size_t)c * 2048 + lane * 8];
        const bf16x8 vf00 = *(const bf16x8*)&vb[0];      // (dt0,ks0)
        const bf16x8 vf01 = *(const bf16x8*)&vb[512];    // (dt0,ks1)
        const bf16x8 vf10 = *(const bf16x8*)&vb[1024];   // (dt1,ks0)
        const bf16x8 vf11 = *(const bf16x8*)&vb[1536];   // (dt1,ks1)

        if (bias != 0.0f) {                  // benchmark has sector_bias == 0
            const float bn = bias * 1.44269504f;
#pragma unroll
            for (int r = 0; r < 16; ++r) {
                const int kl = (r & 3) + 8 * (r >> 2) + 4 * hh;
                sx[r] += bn * swb[c * 32 + kl];
            }
        }
        if (c == p) {                        // diagonal chunk: causal mask (key kl <= q hl)
#pragma unroll
            for (int r = 0; r < 16; ++r) {
                const int kl = (r & 3) + 8 * (r >> 2) + 4 * hh;
                sx[r] = (kl <= hl) ? sx[r] : -1e30f;
            }
        }
#pragma unroll
        for (int r = 0; r < 16; ++r) sx[r] = exp2f(sx[r]);

        // pack P -> bf16 A-fragment: 8 cvt_pk + 4 permlane32_swap
        unsigned wds[8];
#pragma unroll
        for (int g2 = 0; g2 < 4; ++g2) {
            wds[g2 * 2]     = cvtpk(sx[g2 * 4],     sx[g2 * 4 + 1]);
            wds[g2 * 2 + 1] = cvtpk(sx[g2 * 4 + 2], sx[g2 * 4 + 3]);
        }
        bf16x8 pf[2];
#pragma unroll
        for (int ks = 0; ks < 2; ++ks) {
            unsigned a0, a1, b0, b1;
            plswap(wds[4 * ks],     wds[4 * ks + 2], a0, a1);
            plswap(wds[4 * ks + 1], wds[4 * ks + 3], b0, b1);
            union { unsigned u[4]; bf16x8 v; } pk_;
            pk_.u[0] = a0; pk_.u[1] = b0;
            pk_.u[2] = a1; pk_.u[3] = b1;
            pf[ks] = pk_.v;
        }

        // rowsum via ones-MFMA, accumulated straight into lrow
        lrow = __builtin_amdgcn_mfma_f32_32x32x16_bf16(pf[0], onef, lrow, 0, 0, 0);
        lrow = __builtin_amdgcn_mfma_f32_32x32x16_bf16(pf[1], onef, lrow, 0, 0, 0);

        // O += P V
        oacc[0] = __builtin_amdgcn_mfma_f32_32x32x16_bf16(pf[0], vf00, oacc[0], 0, 0, 0);
        oacc[0] = __builtin_amdgcn_mfma_f32_32x32x16_bf16(pf[1], vf01, oacc[0], 0, 0, 0);
        oacc[1] = __builtin_amdgcn_mfma_f32_32x32x16_bf16(pf[0], vf10, oacc[1], 0, 0, 0);
        oacc[1] = __builtin_amdgcn_mfma_f32_32x32x16_bf16(pf[1], vf11, oacc[1], 0, 0, 0);
    }

    // combine the two waves' partials (additive under constant-max softmax)
    __syncthreads();
    if (wid == 1) {
#pragma unroll
        for (int dt = 0; dt < 2; ++dt)
#pragma unroll
            for (int r = 0; r < 16; ++r) Cmb[(dt * 16 + r) * 64 + lane] = oacc[dt][r];
#pragma unroll
        for (int r = 0; r < 16; ++r) Cmb[2048 + r * 64 + lane] = lrow[r];
    }
    __syncthreads();
    if (wid == 0) {
#pragma unroll
        for (int r = 0; r < 16; ++r) {
            const float li = 1.0f / (lrow[r] + Cmb[2048 + r * 64 + lane]);
            const int row = (r & 3) + 8 * (r >> 2) + 4 * hh;
            const int qr = q0 + row;
#pragma unroll
            for (int dt = 0; dt < 2; ++dt) {
                const float ov = oacc[dt][r] + Cmb[(dt * 16 + r) * 64 + lane];
                attn[(size_t)(b * T + qr) * 1024 + h * 64 + dt * 32 + hl] = f2bf(ov * li);
            }
        }
    }
}

extern "C" void kernel_launch(void* const* d_in, const int* in_sizes, int n_in,
                              void* d_out, int out_size, void* d_ws, size_t ws_size,
                              hipStream_t stream) {
    const float* x  = (const float*)d_in[0];
    const float* Wq = (const float*)d_in[1];
    const float* Wk = (const float*)d_in[2];
    const float* Wv = (const float*)d_in[3];
    const float* Wo = (const float*)d_in[4];
    const float* bo = (const float*)d_in[5];
    const float* sb = (const float*)d_in[6];
    const float* sw = (const float*)d_in[7];

    const size_t QKV_SZ = 4194304;   // shorts per q/k/v tensor
    const size_t W_SZ   = 1048576;   // shorts per weight matrix
    unsigned short* ws16 = (unsigned short*)d_ws;
    const bool big = ws_size >= 2 * (4 * QKV_SZ + 4 * W_SZ);  // 41.9 MB

    if (big) {
        unsigned short* xb    = ws16;            // x (A-fragment-major)
        unsigned short* Wb3   = xb + QKV_SZ;     // Wq,Wk,Wv (row-major)
        unsigned short* Wob   = Wb3 + 3 * W_SZ;  // Wo (row-major)
        unsigned short* qkv   = Wob + W_SZ;      // q,k,v (flash-fragment-major)
        unsigned short* attnb = xb;              // overlay x (dead after QKV gemm)

        cvt_all<<<4096, 256, 0, stream>>>(x, Wq, Wk, Wv, Wo, xb, 1, 1048576);
        gemm_qkv<1><<<dim3(8, 32, 3), 512, 0, stream>>>(xb, Wb3, qkv, sw);
        flash_attn<<<2048, 128, 0, stream>>>(qkv, qkv + QKV_SZ, qkv + 2 * QKV_SZ,
                                             sb, sw, attnb);
        gemm_proj<<<dim3(8, 64), 512, 0, stream>>>(attnb, Wob, (float*)d_out, bo);
    } else {                                     // 33.6 MB fallback
        unsigned short* qkv   = ws16;
        unsigned short* attnb = qkv + 3 * QKV_SZ;
        unsigned short* Wb3   = attnb;           // overlay attn (dead until flash)
        unsigned short* Wob   = qkv;             // overlay q (dead after flash)

        cvt_all<<<1536, 256, 0, stream>>>(x, Wq, Wk, Wv, Wo, Wb3, 0, 393216);
        gemm_qkv<0><<<dim3(8, 32, 3), 512, 0, stream>>>(x, Wb3, qkv, sw);
        flash_attn<<<2048, 128, 0, stream>>>(qkv, qkv + QKV_SZ, qkv + 2 * QKV_SZ,
                                             sb, sw, attnb);
        cvt_all<<<512, 256, 0, stream>>>(x, Wo, Wo, Wo, Wo, Wob, 0, 131072);
        gemm_proj<<<dim3(8, 64), 512, 0, stream>>>(attnb, Wob, (float*)d_out, bo);
    }
}